// Round 1
// baseline (178.985 us; speedup 1.0000x reference)
//
#include <hip/hip_runtime.h>
#include <hip/hip_bf16.h>

#define T_DIM 2048
#define N_DIM 128
#define K_DIM 256
#define C_DIM 40
#define SEG 256
#define SEGLEN 8      // T_DIM / SEG
#define GRP 8
#define SEGPERGRP 32  // SEG / GRP

typedef __attribute__((ext_vector_type(8))) short bf16x8;
typedef __attribute__((ext_vector_type(4))) float f32x4v;

__device__ __forceinline__ unsigned pack_bf16(float a, float b) {
    union { float f; unsigned u; } ua, ub;
    ua.f = a; ub.f = b;
    unsigned ra = (ua.u + 0x7FFFu + ((ua.u >> 16) & 1u)) >> 16;
    unsigned rb = (ub.u + 0x7FFFu + ((ub.u >> 16) & 1u)) >> 16;
    return (ra & 0xFFFFu) | (rb << 16);
}

__device__ __forceinline__ float fast_tanh(float v) {
    // tanh(v) = 1 - 2/(e^{2v}+1); exact at +-inf, fine near 0 for our tolerance
    float e = __expf(2.f * v);
    return 1.f - 2.f / (e + 1.f);
}

// ---------------- Phase 1: y = 5*tanh(x W^T + b), bf16 MFMA ----------------
// block = 256 thr (4 waves), tile = 64 rows x 48 cols (40 real), K=256 staged.
__global__ __launch_bounds__(256) void k_gemm_tanh(
    const float* __restrict__ x, const float* __restrict__ W,
    const float* __restrict__ b, float* __restrict__ y)
{
    __shared__ __align__(16) unsigned shA[8192];  // 64 rows x 512B (bf16), XOR-swizzled
    __shared__ __align__(16) unsigned shB[6144];  // 48 rows x 512B (bf16), XOR-swizzled
    const int tid = threadIdx.x;
    const size_t row0 = (size_t)blockIdx.x * 64;

    // stage W (pad rows 40..47 with zeros), bf16, swizzle byte ^= (row&7)<<4
    for (int i = tid; i < 6144; i += 256) {
        int flat = i * 2;          // bf16 element index
        int r = flat >> 8;         // 0..47
        int k = flat & 255;        // even
        float v0 = 0.f, v1 = 0.f;
        if (r < C_DIM) { v0 = W[r * K_DIM + k]; v1 = W[r * K_DIM + k + 1]; }
        int byte = (k * 2) ^ ((r & 7) << 4);
        shB[(r * 512 + byte) >> 2] = pack_bf16(v0, v1);
    }

    // stage x tile: 64 rows x 256 f32 -> bf16 LDS (coalesced float4 reads)
    #pragma unroll
    for (int it = 0; it < 16; ++it) {
        int flat = it * 1024 + tid * 4;  // f32 index in tile
        int r = flat >> 8;
        int k = flat & 255;              // multiple of 4
        float4 v = *reinterpret_cast<const float4*>(x + (row0 + r) * K_DIM + k);
        int byte = (k * 2) ^ ((r & 7) << 4);
        int idx = (r * 512 + byte) >> 2;
        shA[idx] = pack_bf16(v.x, v.y);
        shA[idx + 1] = pack_bf16(v.z, v.w);
    }
    __syncthreads();

    const int lane = tid & 63;
    const int wave = tid >> 6;     // 0..3 -> rows wave*16..+15
    const int lr = lane & 15;
    const int kg = lane >> 4;      // 0..3

    f32x4v acc0 = {0.f, 0.f, 0.f, 0.f};
    f32x4v acc1 = {0.f, 0.f, 0.f, 0.f};
    f32x4v acc2 = {0.f, 0.f, 0.f, 0.f};
    const char* cA = reinterpret_cast<const char*>(shA);
    const char* cB = reinterpret_cast<const char*>(shB);
    const int arow = wave * 16 + lr;
    const int aswz = (arow & 7) << 4;
    const int bswz = (lr & 7) << 4;  // (16+lr)&7 == (32+lr)&7 == lr&7

    #pragma unroll
    for (int kt = 0; kt < 8; ++kt) {
        int kb2 = (kt * 32 + kg * 8) * 2;  // byte offset of lane's 8-elem k-chunk
        bf16x8 af  = *reinterpret_cast<const bf16x8*>(cA + arow * 512 + (kb2 ^ aswz));
        bf16x8 bf0 = *reinterpret_cast<const bf16x8*>(cB + (lr)      * 512 + (kb2 ^ bswz));
        bf16x8 bf1 = *reinterpret_cast<const bf16x8*>(cB + (16 + lr) * 512 + (kb2 ^ bswz));
        bf16x8 bf2 = *reinterpret_cast<const bf16x8*>(cB + (32 + lr) * 512 + (kb2 ^ bswz));
        acc0 = __builtin_amdgcn_mfma_f32_16x16x32_bf16(af, bf0, acc0, 0, 0, 0);
        acc1 = __builtin_amdgcn_mfma_f32_16x16x32_bf16(af, bf1, acc1, 0, 0, 0);
        acc2 = __builtin_amdgcn_mfma_f32_16x16x32_bf16(af, bf2, acc2, 0, 0, 0);
    }

    // C/D layout: col = lane&15, row = (lane>>4)*4 + reg
    float bv0 = b[lr];
    float bv1 = b[16 + lr];
    float bv2 = (lr < 8) ? b[32 + lr] : 0.f;
    #pragma unroll
    for (int r = 0; r < 4; ++r) {
        size_t grow = row0 + wave * 16 + kg * 4 + r;
        float* yr = y + grow * C_DIM;
        yr[lr]      = 5.f * fast_tanh(acc0[r] + bv0);
        yr[16 + lr] = 5.f * fast_tanh(acc1[r] + bv1);
        if (lr < 8) yr[32 + lr] = 5.f * fast_tanh(acc2[r] + bv2);
    }
}

// ---------------- Phase 2a: per-segment transition matrices (linear space) --
// thread = (n, s, c): propagate e_c through SEGLEN steps; store normalized
// column + log-scale.  segv[((s*8+c)*8+j)*128+n], segl[(s*8+c)*128+n]
__global__ __launch_bounds__(256) void k_seg(
    const float* __restrict__ y, float* __restrict__ segv, float* __restrict__ segl)
{
    int tid = blockIdx.x * 256 + threadIdx.x;
    int c = tid & 7;
    int n = (tid >> 3) & 127;
    int s = tid >> 10;

    float p[8];
    #pragma unroll
    for (int i = 0; i < 8; ++i) p[i] = (i == c) ? 1.f : 0.f;

    for (int t = s * SEGLEN; t < s * SEGLEN + SEGLEN; ++t) {
        const float* yr = y + ((size_t)t * N_DIM + n) * C_DIM;
        float sc[40];
        #pragma unroll
        for (int i = 0; i < 10; ++i) {
            float4 v = reinterpret_cast<const float4*>(yr)[i];
            sc[i * 4 + 0] = v.x; sc[i * 4 + 1] = v.y;
            sc[i * 4 + 2] = v.z; sc[i * 4 + 3] = v.w;
        }
        float q[8];
        #pragma unroll
        for (int j = 0; j < 4; ++j) {           // flip states: all 8 sources
            float acc = 0.f;
            #pragma unroll
            for (int i = 0; i < 8; ++i) acc += p[i] * __expf(sc[j * 8 + i]);
            q[j] = acc;
        }
        #pragma unroll
        for (int j = 0; j < 4; ++j)             // flop states: 2 sources
            q[4 + j] = p[j] * __expf(sc[32 + j]) + p[4 + j] * __expf(sc[36 + j]);
        #pragma unroll
        for (int i = 0; i < 8; ++i) p[i] = q[i];
    }
    float sum = 0.f;
    #pragma unroll
    for (int i = 0; i < 8; ++i) sum += p[i];
    float inv = 1.f / sum;
    float lg = __logf(sum);
    #pragma unroll
    for (int j = 0; j < 8; ++j)
        segv[(((size_t)s * 8 + c) * 8 + j) * N_DIM + n] = p[j] * inv;
    segl[((size_t)s * 8 + c) * N_DIM + n] = lg;
}

// ---------------- Phase 2b: combine 32 segments per group ------------------
// thread = (n, cc, g): column cc of group-g matrix.
__global__ __launch_bounds__(256) void k_grp(
    const float* __restrict__ segv, const float* __restrict__ segl,
    float* __restrict__ grpv, float* __restrict__ grpl)
{
    int tid = blockIdx.x * 256 + threadIdx.x;  // 8192 total
    int n = tid & 127;
    int cc = (tid >> 7) & 7;
    int g = tid >> 10;

    float u[8];
    #pragma unroll
    for (int i = 0; i < 8; ++i) u[i] = (i == cc) ? 1.f : 0.f;
    float logacc = 0.f;

    for (int s = g * SEGPERGRP; s < (g + 1) * SEGPERGRP; ++s) {
        float l[8];
        #pragma unroll
        for (int i = 0; i < 8; ++i) l[i] = segl[((size_t)s * 8 + i) * N_DIM + n];
        float m = l[0];
        #pragma unroll
        for (int i = 1; i < 8; ++i) m = fmaxf(m, l[i]);
        float nu[8] = {0.f, 0.f, 0.f, 0.f, 0.f, 0.f, 0.f, 0.f};
        #pragma unroll
        for (int i = 0; i < 8; ++i) {
            float wi = u[i] * __expf(l[i] - m);
            #pragma unroll
            for (int j = 0; j < 8; ++j)
                nu[j] += wi * segv[(((size_t)s * 8 + i) * 8 + j) * N_DIM + n];
        }
        float sum = 0.f;
        #pragma unroll
        for (int j = 0; j < 8; ++j) sum += nu[j];
        float inv = 1.f / sum;
        #pragma unroll
        for (int j = 0; j < 8; ++j) u[j] = nu[j] * inv;
        logacc += m + __logf(sum);
    }
    #pragma unroll
    for (int j = 0; j < 8; ++j)
        grpv[(((size_t)g * 8 + cc) * 8 + j) * N_DIM + n] = u[j];
    grpl[((size_t)g * 8 + cc) * N_DIM + n] = logacc;
}

// ---------------- Phase 2c: fold 8 groups into logZ/T ----------------------
__global__ void k_fin(const float* __restrict__ grpv, const float* __restrict__ grpl,
                      float* __restrict__ lz)
{
    int n = threadIdx.x;  // 128
    float p[8] = {0.25f, 0.25f, 0.25f, 0.25f, 0.f, 0.f, 0.f, 0.f};
    float logZ = 1.3862943611198906f;  // log(4) = logsumexp(fwd0)

    for (int g = 0; g < GRP; ++g) {
        float l[8];
        #pragma unroll
        for (int i = 0; i < 8; ++i) l[i] = grpl[((size_t)g * 8 + i) * N_DIM + n];
        float m = l[0];
        #pragma unroll
        for (int i = 1; i < 8; ++i) m = fmaxf(m, l[i]);
        float nu[8] = {0.f, 0.f, 0.f, 0.f, 0.f, 0.f, 0.f, 0.f};
        #pragma unroll
        for (int i = 0; i < 8; ++i) {
            float wi = p[i] * __expf(l[i] - m);
            #pragma unroll
            for (int j = 0; j < 8; ++j)
                nu[j] += wi * grpv[(((size_t)g * 8 + i) * 8 + j) * N_DIM + n];
        }
        float sum = 0.f;
        #pragma unroll
        for (int j = 0; j < 8; ++j) sum += nu[j];
        float inv = 1.f / sum;
        #pragma unroll
        for (int j = 0; j < 8; ++j) p[j] = nu[j] * inv;
        logZ += m + __logf(sum);
    }
    lz[n] = logZ * (1.f / (float)T_DIM);
}

// ---------------- Phase 3: out -= logZ[n]/T (in place) ---------------------
__global__ __launch_bounds__(256) void k_sub(float* __restrict__ out,
                                             const float* __restrict__ lz)
{
    int i = blockIdx.x * 256 + threadIdx.x;   // float4 index; 2621440 total
    int n = (i / 10) & 127;                   // i = (t*128+n)*10 + c4
    float d = lz[n];
    float4* o = reinterpret_cast<float4*>(out) + i;
    float4 v = *o;
    v.x -= d; v.y -= d; v.z -= d; v.w -= d;
    *o = v;
}

extern "C" void kernel_launch(void* const* d_in, const int* in_sizes, int n_in,
                              void* d_out, int out_size, void* d_ws, size_t ws_size,
                              hipStream_t stream) {
    const float* x = (const float*)d_in[0];
    const float* W = (const float*)d_in[1];
    const float* b = (const float*)d_in[2];
    float* out = (float*)d_out;
    float* ws = (float*)d_ws;

    float* segv = ws;                  // SEG*8*8*128      = 2,097,152 f32
    float* segl = ws + 2097152;        // SEG*8*128        =   262,144 f32
    float* grpv = ws + 2359296;        // GRP*8*8*128      =    65,536 f32
    float* grpl = ws + 2424832;        // GRP*8*128        =     8,192 f32
    float* lz   = ws + 2433024;        // 128 f32

    k_gemm_tanh<<<4096, 256, 0, stream>>>(x, W, b, out);   // y -> d_out
    k_seg<<<1024, 256, 0, stream>>>(out, segv, segl);
    k_grp<<<32, 256, 0, stream>>>(segv, segl, grpv, grpl);
    k_fin<<<1, 128, 0, stream>>>(grpv, grpl, lz);
    k_sub<<<10240, 256, 0, stream>>>(out, lz);
}